// Round 10
// baseline (1493.264 us; speedup 1.0000x reference)
//
#include <hip/hip_runtime.h>
#include <hip/hip_bf16.h>
#include <cstdint>

// Problem constants
#define B_  16
#define S_  1024
#define D_  512
#define H_  8
#define L_  32
#define DH_ 64

typedef __attribute__((ext_vector_type(8))) short bf16x8;
typedef __attribute__((ext_vector_type(4))) float f32x4;

__device__ __forceinline__ float bf2f(unsigned short u) {
    union { unsigned int u; float f; } x; x.u = ((unsigned int)u) << 16; return x.f;
}
__device__ __forceinline__ unsigned short f2bf(float f) {
    union { float f; unsigned int u; } x; x.f = f;
    unsigned int r = x.u + 0x7fffu + ((x.u >> 16) & 1u);
    return (unsigned short)(r >> 16);
}

// agent-scope (device) coherent access helpers: cache-bypassing, hit the LLC.
__device__ __forceinline__ float ld_dev(const float* p) {
    return __hip_atomic_load(p, __ATOMIC_RELAXED, __HIP_MEMORY_SCOPE_AGENT);
}

// ---------------- prep kernels ----------------

__global__ void k_conv(const float* __restrict__ in, unsigned short* __restrict__ out, int n) {
    int i = (blockIdx.x * 256 + threadIdx.x) * 4;
    int stride = gridDim.x * 1024;
    for (; i < n; i += stride) {
        float4 v = *reinterpret_cast<const float4*>(in + i);
        out[i + 0] = f2bf(v.x); out[i + 1] = f2bf(v.y);
        out[i + 2] = f2bf(v.z); out[i + 3] = f2bf(v.w);
    }
}

// out[c*R + r] = bf16(in[r*C + c]);   block (32,8), grid (C/32, R/32)
__global__ void k_transpose_bf(const float* __restrict__ in, unsigned short* __restrict__ out,
                               int R, int C) {
    __shared__ float tile[32][33];
    int c0 = blockIdx.x * 32, r0 = blockIdx.y * 32;
    int tx = threadIdx.x, ty = threadIdx.y;
#pragma unroll
    for (int i = 0; i < 4; i++)
        tile[ty + i * 8][tx] = in[(size_t)(r0 + ty + i * 8) * C + c0 + tx];
    __syncthreads();
#pragma unroll
    for (int i = 0; i < 4; i++)
        out[(size_t)(c0 + ty + i * 8) * R + r0 + tx] = f2bf(tile[tx][ty + i * 8]);
}

// strip W_ih[:, :512] (row stride 515) into dense bf16 [1536,512]
__global__ void k_conv_wih(const float* __restrict__ in, unsigned short* __restrict__ out) {
    int i = blockIdx.x * 256 + threadIdx.x;   // 786432 total
    int j = i >> 9, k = i & 511;
    out[i] = f2bf(in[j * 515 + k]);
}

// b_f[j] = b_ih[j] + sum_k W_ih[j,k]*bo[k];  Wd[j,c] = W_ih[j,512+c]
__global__ void k_bf_wd(const float* __restrict__ Wih, const float* __restrict__ bih,
                        const float* __restrict__ bo, float* __restrict__ bf_,
                        float* __restrict__ Wd) {
    int j = blockIdx.x * 256 + threadIdx.x;
    if (j >= 1536) return;
    float acc = bih[j];
    for (int k = 0; k < 512; k++) acc += Wih[(size_t)j * 515 + k] * bo[k];
    bf_[j] = acc;
    Wd[j * 3 + 0] = Wih[(size_t)j * 515 + 512];
    Wd[j * 3 + 1] = Wih[(size_t)j * 515 + 513];
    Wd[j * 3 + 2] = Wih[(size_t)j * 515 + 514];
}

// gacc[l][bi][j]: j<1536 -> dterm (b_f + teacher-forcing term); j>=1536 -> b_hh[j-1536]
// Pre-fills the atomicAdd accumulation target for k_decode (re-run each launch).
__global__ void k_dterm2(const float* __restrict__ target, const float* __restrict__ Wd,
                         const float* __restrict__ bf_, const float* __restrict__ bhh,
                         float* __restrict__ gacc) {
    int i = blockIdx.x * 256 + threadIdx.x;   // 32*16*3072 = 1,572,864
    int j = i % 3072; int bl = i / 3072; int b = bl % 16; int l = bl / 16;
    float acc;
    if (j < 1536) {
        acc = bf_[j];
        if (l > 0) {
            const float* tg = target + ((size_t)b * L_ + (l - 1)) * 3;
            acc += tg[0] * Wd[j * 3 + 0] + tg[1] * Wd[j * 3 + 1] + tg[2] * Wd[j * 3 + 2];
        }
    } else {
        acc = bhh[j - 1536];
    }
    gacc[i] = acc;
}

// ---------------- MFMA GEMM: C[M,N] = A[M,K] @ B[N,K]^T (+bias[N]) ----------------
template <bool BF16OUT>
__global__ __launch_bounds__(256) void k_gemm_bt(
    const unsigned short* __restrict__ A, const unsigned short* __restrict__ Bm,
    void* __restrict__ Cout, const float* __restrict__ bias, int M, int N, int Kd) {
    __shared__ unsigned short As[128 * 64];
    __shared__ unsigned short Bs[128 * 64];
    const int t = threadIdx.x;
    const int lane = t & 63;
    const int w = t >> 6, wr = w >> 1, wc = w & 1;
    const int m0 = blockIdx.x * 128, n0 = blockIdx.y * 128;
    f32x4 acc[4][4];
#pragma unroll
    for (int i = 0; i < 4; i++)
#pragma unroll
        for (int j = 0; j < 4; j++) acc[i][j] = (f32x4){0.f, 0.f, 0.f, 0.f};

    const int rowt = t >> 3, colt = (t & 7) * 8;
    for (int k0 = 0; k0 < Kd; k0 += 64) {
#pragma unroll
        for (int i = 0; i < 4; i++) {
            int row = i * 32 + rowt;
            __builtin_amdgcn_global_load_lds(
                (const __attribute__((address_space(1))) unsigned int*)(A + (size_t)(m0 + row) * Kd + k0 + colt),
                (__attribute__((address_space(3))) unsigned int*)(As + (i * 256 + t) * 8), 16, 0, 0);
            __builtin_amdgcn_global_load_lds(
                (const __attribute__((address_space(1))) unsigned int*)(Bm + (size_t)(n0 + row) * Kd + k0 + colt),
                (__attribute__((address_space(3))) unsigned int*)(Bs + (i * 256 + t) * 8), 16, 0, 0);
        }
        asm volatile("s_waitcnt vmcnt(0)" ::: "memory");
        __syncthreads();
#pragma unroll
        for (int kk = 0; kk < 2; kk++) {
            bf16x8 af[4], bfr[4];
#pragma unroll
            for (int mi = 0; mi < 4; mi++)
                af[mi] = *reinterpret_cast<const bf16x8*>(
                    As + (wr * 64 + mi * 16 + (lane & 15)) * 64 + kk * 32 + (lane >> 4) * 8);
#pragma unroll
            for (int ni = 0; ni < 4; ni++)
                bfr[ni] = *reinterpret_cast<const bf16x8*>(
                    Bs + (wc * 64 + ni * 16 + (lane & 15)) * 64 + kk * 32 + (lane >> 4) * 8);
#pragma unroll
            for (int mi = 0; mi < 4; mi++)
#pragma unroll
                for (int ni = 0; ni < 4; ni++)
                    acc[mi][ni] = __builtin_amdgcn_mfma_f32_16x16x32_bf16(af[mi], bfr[ni], acc[mi][ni], 0, 0, 0);
        }
        __syncthreads();
    }
    const int rr = (lane >> 4) * 4, cc = lane & 15;
#pragma unroll
    for (int mi = 0; mi < 4; mi++) {
#pragma unroll
        for (int ni = 0; ni < 4; ni++) {
            int col = n0 + wc * 64 + ni * 16 + cc;
            float bv = bias ? bias[col] : 0.f;
            int rowb = m0 + wr * 64 + mi * 16 + rr;
#pragma unroll
            for (int r = 0; r < 4; r++) {
                float v = acc[mi][ni][r] + bv;
                if (BF16OUT) ((unsigned short*)Cout)[(size_t)(rowb + r) * N + col] = f2bf(v);
                else         ((float*)Cout)[(size_t)(rowb + r) * N + col] = v;
            }
        }
    }
}

// ---- group barrier: 8 head-blocks of one bi, one counter per (bi, step) ----
// Every thread drains its outstanding vmem (atomicAdds!) before arriving.
// No __threadfence (round-6 lesson: it flushes L1/L2). Counter at LLC.
__device__ __forceinline__ void group_barrier(unsigned* bar, unsigned tgt) {
    asm volatile("s_waitcnt vmcnt(0)" ::: "memory");
    __syncthreads();
    if (threadIdx.x == 0) {
        __hip_atomic_fetch_add(bar, 1u, __ATOMIC_RELAXED, __HIP_MEMORY_SCOPE_AGENT);
        while (__hip_atomic_load(bar, __ATOMIC_RELAXED, __HIP_MEMORY_SCOPE_AGENT) < tgt)
            __builtin_amdgcn_s_sleep(1);
    }
    __syncthreads();
}

// ---------------- persistent decode: block = (bi, head), 1 barrier/step ----------------
// grid 128 x 1024 (16 waves), 1 block/CU. Per step, block (bi,hd):
//   full-head attention (ssum+pv in-block, cross written normalized), then
//   gi_partial = WfT[hd-rows]·attn_h, gh_partial = WhhT[hd-rows]·h_h -> atomicAdd gacc,
//   ONE 8-block barrier, then replicated gate math from gacc updates LDS-local h.
// No h handoff, no pv/ssum buffers, no second barrier, no k_norm.
__global__ __launch_bounds__(1024, 4) void k_decode(
    const unsigned short* __restrict__ K16, const unsigned short* __restrict__ V16,
    const unsigned short* __restrict__ Wq16, const float* __restrict__ bq,
    const unsigned short* __restrict__ WfT16, const unsigned short* __restrict__ WhhT16,
    float* __restrict__ gacc, const float* __restrict__ e_last,
    const float* __restrict__ Wout, const float* __restrict__ bout,
    float* __restrict__ dout, float* __restrict__ hfin, float* __restrict__ cross,
    unsigned* __restrict__ bars) {
    const int t = threadIdx.x, lane = t & 63, w = t >> 6;   // 16 waves
    const int bi = blockIdx.x >> 3, hd = blockIdx.x & 7;

    __shared__ float hsh[512];     // replicated h (local, never round-trips)
    __shared__ float qsh[64];
    __shared__ float esh[1024];
    __shared__ float red[1024];
    __shared__ float pvred[1024];  // [16 waves][64 d]
    __shared__ float ash[64];      // this head's normalized attention
    __shared__ float dsh[1536];
    __shared__ float wred[16];
    __shared__ float sh_ssinv;

    const size_t base = (size_t)bi * (S_ * D_) + (size_t)hd * (S_ * DH_);

    if (t < 512) hsh[t] = e_last[bi * 512 + t];
    __syncthreads();

    for (int l = 0; l < L_; l++) {
        // ---- q-proj: 64 cols x 16 k-parts of 32 ----
        {
            const int c = t & 63, kp = t >> 6;
            const unsigned short* wrow = Wq16 + (size_t)(hd * 64 + c) * 512 + kp * 32;
            float qa = 0.f;
#pragma unroll
            for (int kk = 0; kk < 4; kk++) {
                bf16x8 wv = *reinterpret_cast<const bf16x8*>(wrow + kk * 8);
#pragma unroll
                for (int e = 0; e < 8; e++)
                    qa += hsh[kp * 32 + kk * 8 + e] * bf2f((unsigned short)wv[e]);
            }
            red[t] = qa;
        }
        __syncthreads();
        if (t < 64) {
            float s = bq[hd * 64 + t];
#pragma unroll
            for (int p = 0; p < 16; p++) s += red[p * 64 + t];
            qsh[t] = s * (1.f / 32.f);
        }
        __syncthreads();

        // ---- scores: thread t = s-row t; K from L2; max-free exp (scores O(0.3)) ----
        {
            const unsigned short* kr = K16 + base + (size_t)t * 64;
            float sc = 0.f;
#pragma unroll
            for (int c8 = 0; c8 < 8; c8++) {
                bf16x8 kv = *reinterpret_cast<const bf16x8*>(kr + c8 * 8);
#pragma unroll
                for (int e = 0; e < 8; e++)
                    sc += qsh[c8 * 8 + e] * bf2f((unsigned short)kv[e]);
            }
            float e = __expf(sc);
            esh[t] = e;
            float wsum = e;
#pragma unroll
            for (int off = 1; off < 64; off <<= 1) wsum += __shfl_xor(wsum, off);
            if (lane == 0) wred[w] = wsum;
        }
        __syncthreads();
        if (t == 0) {
            float s = 0.f;
#pragma unroll
            for (int i = 0; i < 16; i++) s += wred[i];
            sh_ssinv = 1.f / s;
        }
        __syncthreads();
        const float ssinv = sh_ssinv;
        cross[((size_t)(bi * 8 + hd) * 32 + l) * 1024 + t] = esh[t] * ssinv;   // normalized

        // ---- PV: lane -> (d-octet o, sr); rows sr+128i; V from L2 ----
        {
            const int o = lane & 7, sr = w * 8 + (lane >> 3);
            float acc[8];
#pragma unroll
            for (int e2 = 0; e2 < 8; e2++) acc[e2] = 0.f;
            const unsigned short* vb = V16 + base + (size_t)sr * 64 + o * 8;
#pragma unroll
            for (int i = 0; i < 8; i++) {
                bf16x8 vv = *reinterpret_cast<const bf16x8*>(vb + (size_t)i * 128 * 64);
                float ev = esh[sr + i * 128];
#pragma unroll
                for (int e2 = 0; e2 < 8; e2++)
                    acc[e2] += ev * bf2f((unsigned short)vv[e2]);
            }
#pragma unroll
            for (int off = 8; off < 64; off <<= 1)
#pragma unroll
                for (int e2 = 0; e2 < 8; e2++)
                    acc[e2] += __shfl_xor(acc[e2], off);
            if (lane < 8) {
#pragma unroll
                for (int e2 = 0; e2 < 8; e2++)
                    pvred[w * 64 + lane * 8 + e2] = acc[e2];
            }
        }
        __syncthreads();
        if (t < 64) {
            float s = 0.f;
#pragma unroll
            for (int i = 0; i < 16; i++) s += pvred[i * 64 + t];
            ash[t] = s * ssinv;   // this head's attn slice, in-block
        }
        __syncthreads();

        // ---- gi/gh partial GEMVs (transposed weights, coalesced) -> atomicAdd ----
        float* g = gacc + ((size_t)l * 16 + bi) * 3072;
        if (t < 768) {
            const unsigned int* wf = (const unsigned int*)WfT16;
            const unsigned int* wh = (const unsigned int*)WhhT16;
            float gi0 = 0.f, gi1 = 0.f, gh0 = 0.f, gh1 = 0.f;
#pragma unroll 8
            for (int k = 0; k < 64; k++) {
                unsigned int uf = wf[(size_t)(hd * 64 + k) * 768 + t];
                unsigned int uh = wh[(size_t)(hd * 64 + k) * 768 + t];
                float a = ash[k], b = hsh[hd * 64 + k];
                gi0 += a * bf2f((unsigned short)(uf & 0xffffu));
                gi1 += a * bf2f((unsigned short)(uf >> 16));
                gh0 += b * bf2f((unsigned short)(uh & 0xffffu));
                gh1 += b * bf2f((unsigned short)(uh >> 16));
            }
            atomicAdd(g + 2 * t, gi0);
            atomicAdd(g + 2 * t + 1, gi1);
            atomicAdd(g + 1536 + 2 * t, gh0);
            atomicAdd(g + 1536 + 2 * t + 1, gh1);
        }

        // ---- ONE barrier per step: 8 head-blocks of this bi ----
        group_barrier(bars + bi * 32 + l, 8u);

        // ---- replicated gates from gacc (LLC reads); update LDS-local h ----
        float hnew_reg = 0.f;
        if (t < 512) {
            float gi_r = ld_dev(g + t),        gi_z = ld_dev(g + 512 + t),  gi_n = ld_dev(g + 1024 + t);
            float gh_r = ld_dev(g + 1536 + t), gh_z = ld_dev(g + 2048 + t), gh_n = ld_dev(g + 2560 + t);
            float r = 1.f / (1.f + __expf(-(gi_r + gh_r)));
            float z = 1.f / (1.f + __expf(-(gi_z + gh_z)));
            float n = tanhf(gi_n + r * gh_n);
            hnew_reg = (1.f - z) * n + z * hsh[t];
        }
        __syncthreads();
        if (t < 512) {
            hsh[t] = hnew_reg;
            if (hd == 0) {
                dsh[t]        = hnew_reg * Wout[t];
                dsh[512 + t]  = hnew_reg * Wout[512 + t];
                dsh[1024 + t] = hnew_reg * Wout[1024 + t];
            }
        }
        __syncthreads();
        if (hd == 0 && w < 3) {
            float s = 0.f;
            for (int i = lane; i < 512; i += 64) s += dsh[w * 512 + i];
#pragma unroll
            for (int off = 1; off < 64; off <<= 1) s += __shfl_xor(s, off);
            if (lane == 0) dout[((size_t)bi * 32 + l) * 3 + w] = s + bout[w];
        }
        __syncthreads();
    }
    if (hd == 0 && t < 512) hfin[bi * 512 + t] = hsh[t];
}

// ---------------- launch ----------------
extern "C" void kernel_launch(void* const* d_in, const int* in_sizes, int n_in,
                              void* d_out, int out_size, void* d_ws, size_t ws_size,
                              hipStream_t stream) {
    (void)in_sizes; (void)n_in; (void)out_size; (void)ws_size;
    const float* e_all  = (const float*)d_in[0];
    const float* e_last = (const float*)d_in[1];
    const float* target = (const float*)d_in[2];
    const float* Wq     = (const float*)d_in[3];
    const float* bq     = (const float*)d_in[4];
    const float* Wk     = (const float*)d_in[5];
    const float* bk     = (const float*)d_in[6];
    const float* Wv     = (const float*)d_in[7];
    const float* bv     = (const float*)d_in[8];
    const float* Wo     = (const float*)d_in[9];
    const float* bo     = (const float*)d_in[10];
    const float* W_ih   = (const float*)d_in[11];
    const float* W_hh   = (const float*)d_in[12];
    const float* b_ih   = (const float*)d_in[13];
    const float* b_hh   = (const float*)d_in[14];
    const float* W_out  = (const float*)d_in[15];
    const float* b_out  = (const float*)d_in[16];
    float* out = (float*)d_out;

    char* ws = (char*)d_ws;
    size_t off = 0;
    auto alloc = [&](size_t bytes) -> void* {
        void* p = ws + off; off += (bytes + 255) & ~(size_t)255; return p;
    };
    unsigned short* eA     = (unsigned short*)alloc(16777216);
    unsigned short* K16    = (unsigned short*)alloc(16777216);
    unsigned short* V16    = (unsigned short*)alloc(16777216);
    unsigned short* Wk16   = (unsigned short*)alloc(524288);
    unsigned short* Wv16   = (unsigned short*)alloc(524288);
    unsigned short* Wq16   = (unsigned short*)alloc(524288);
    unsigned short* WhhT16 = (unsigned short*)alloc(1572864);   // [512][1536]
    unsigned short* Wih16  = (unsigned short*)alloc(1572864);
    unsigned short* WoT    = (unsigned short*)alloc(524288);
    unsigned short* WfT16  = (unsigned short*)alloc(1572864);   // [512][1536]
    float* Wf32  = (float*)alloc(3145728);
    float* bf_   = (float*)alloc(6144);
    float* Wd    = (float*)alloc(18432);
    float* gacc  = (float*)alloc(6291456);   // [32][16][3072]
    unsigned* bars = (unsigned*)alloc(2048); // [16][32]

    float* d_outputs = out;          // [16,32,3]
    float* h_fin     = out + 1536;   // [1,16,512]
    float* cross     = out + 9728;   // [16,8,32,1024]

    // one-time prep
    hipMemsetAsync(bars, 0, 2048, stream);
    k_conv<<<2048, 256, 0, stream>>>(e_all, eA, 8388608);
    k_conv<<<256, 256, 0, stream>>>(Wk, Wk16, 262144);
    k_conv<<<256, 256, 0, stream>>>(Wv, Wv16, 262144);
    k_conv<<<256, 256, 0, stream>>>(Wq, Wq16, 262144);
    k_transpose_bf<<<dim3(16, 48), dim3(32, 8), 0, stream>>>(W_hh, WhhT16, 1536, 512);
    k_transpose_bf<<<dim3(16, 16), dim3(32, 8), 0, stream>>>(Wo, WoT, 512, 512);
    k_conv_wih<<<3072, 256, 0, stream>>>(W_ih, Wih16);
    k_bf_wd<<<6, 256, 0, stream>>>(W_ih, b_ih, bo, bf_, Wd);
    k_dterm2<<<6144, 256, 0, stream>>>(target, Wd, bf_, b_hh, gacc);
    k_gemm_bt<true><<<dim3(128, 4), 256, 0, stream>>>(eA, Wk16, K16, bk, 16384, 512, 512);
    k_gemm_bt<true><<<dim3(128, 4), 256, 0, stream>>>(eA, Wv16, V16, bv, 16384, 512, 512);
    k_gemm_bt<false><<<dim3(12, 4), 256, 0, stream>>>(Wih16, WoT, Wf32, nullptr, 1536, 512, 512);
    k_transpose_bf<<<dim3(16, 48), dim3(32, 8), 0, stream>>>(Wf32, WfT16, 1536, 512);

    // persistent decode: one launch, one 8-block barrier per step
    k_decode<<<128, 1024, 0, stream>>>(K16, V16, Wq16, bq, WfT16, WhhT16, gacc, e_last,
                                       W_out, b_out, d_outputs, h_fin, cross, bars);
}

// Round 11
// 794.546 us; speedup vs baseline: 1.8794x; 1.8794x over previous
//
#include <hip/hip_runtime.h>
#include <hip/hip_bf16.h>
#include <cstdint>

// Problem constants
#define B_  16
#define S_  1024
#define D_  512
#define H_  8
#define L_  32
#define DH_ 64

typedef __attribute__((ext_vector_type(8))) short bf16x8;
typedef __attribute__((ext_vector_type(4))) float f32x4;

__device__ __forceinline__ float bf2f(unsigned short u) {
    union { unsigned int u; float f; } x; x.u = ((unsigned int)u) << 16; return x.f;
}
__device__ __forceinline__ unsigned short f2bf(float f) {
    union { float f; unsigned int u; } x; x.f = f;
    unsigned int r = x.u + 0x7fffu + ((x.u >> 16) & 1u);
    return (unsigned short)(r >> 16);
}

// agent-scope (device) coherent access helpers: cache-bypassing, hit the LLC.
__device__ __forceinline__ void st_dev(float* p, float v) {
    __hip_atomic_store(p, v, __ATOMIC_RELAXED, __HIP_MEMORY_SCOPE_AGENT);
}
__device__ __forceinline__ float ld_dev(const float* p) {
    return __hip_atomic_load(p, __ATOMIC_RELAXED, __HIP_MEMORY_SCOPE_AGENT);
}

// ---------------- prep kernels ----------------

__global__ void k_conv(const float* __restrict__ in, unsigned short* __restrict__ out, int n) {
    int i = (blockIdx.x * 256 + threadIdx.x) * 4;
    int stride = gridDim.x * 1024;
    for (; i < n; i += stride) {
        float4 v = *reinterpret_cast<const float4*>(in + i);
        out[i + 0] = f2bf(v.x); out[i + 1] = f2bf(v.y);
        out[i + 2] = f2bf(v.z); out[i + 3] = f2bf(v.w);
    }
}

// out[c*R + r] = bf16(in[r*C + c]);   block (32,8), grid (C/32, R/32)
__global__ void k_transpose_bf(const float* __restrict__ in, unsigned short* __restrict__ out,
                               int R, int C) {
    __shared__ float tile[32][33];
    int c0 = blockIdx.x * 32, r0 = blockIdx.y * 32;
    int tx = threadIdx.x, ty = threadIdx.y;
#pragma unroll
    for (int i = 0; i < 4; i++)
        tile[ty + i * 8][tx] = in[(size_t)(r0 + ty + i * 8) * C + c0 + tx];
    __syncthreads();
#pragma unroll
    for (int i = 0; i < 4; i++)
        out[(size_t)(c0 + ty + i * 8) * R + r0 + tx] = f2bf(tile[tx][ty + i * 8]);
}

// strip W_ih[:, :512] (row stride 515) into dense bf16 [1536,512]
__global__ void k_conv_wih(const float* __restrict__ in, unsigned short* __restrict__ out) {
    int i = blockIdx.x * 256 + threadIdx.x;   // 786432 total
    int j = i >> 9, k = i & 511;
    out[i] = f2bf(in[j * 515 + k]);
}

// b_f[j] = b_ih[j] + sum_k W_ih[j,k]*bo[k];  Wd[j,c] = W_ih[j,512+c]
__global__ void k_bf_wd(const float* __restrict__ Wih, const float* __restrict__ bih,
                        const float* __restrict__ bo, float* __restrict__ bf_,
                        float* __restrict__ Wd) {
    int j = blockIdx.x * 256 + threadIdx.x;
    if (j >= 1536) return;
    float acc = bih[j];
    for (int k = 0; k < 512; k++) acc += Wih[(size_t)j * 515 + k] * bo[k];
    bf_[j] = acc;
    Wd[j * 3 + 0] = Wih[(size_t)j * 515 + 512];
    Wd[j * 3 + 1] = Wih[(size_t)j * 515 + 513];
    Wd[j * 3 + 2] = Wih[(size_t)j * 515 + 514];
}

// gacc[l][bi][j]: j<1536 -> dterm (b_f + teacher-forcing); j>=1536 -> b_hh[j-1536]
__global__ void k_dterm2(const float* __restrict__ target, const float* __restrict__ Wd,
                         const float* __restrict__ bf_, const float* __restrict__ bhh,
                         float* __restrict__ gacc) {
    int i = blockIdx.x * 256 + threadIdx.x;   // 32*16*3072 = 1,572,864
    int j = i % 3072; int bl = i / 3072; int b = bl % 16; int l = bl / 16;
    float acc;
    if (j < 1536) {
        acc = bf_[j];
        if (l > 0) {
            const float* tg = target + ((size_t)b * L_ + (l - 1)) * 3;
            acc += tg[0] * Wd[j * 3 + 0] + tg[1] * Wd[j * 3 + 1] + tg[2] * Wd[j * 3 + 2];
        }
    } else {
        acc = bhh[j - 1536];
    }
    gacc[i] = acc;
}

// ---------------- MFMA GEMM: C[M,N] = A[M,K] @ B[N,K]^T (+bias[N]) ----------------
template <bool BF16OUT>
__global__ __launch_bounds__(256) void k_gemm_bt(
    const unsigned short* __restrict__ A, const unsigned short* __restrict__ Bm,
    void* __restrict__ Cout, const float* __restrict__ bias, int M, int N, int Kd) {
    __shared__ unsigned short As[128 * 64];
    __shared__ unsigned short Bs[128 * 64];
    const int t = threadIdx.x;
    const int lane = t & 63;
    const int w = t >> 6, wr = w >> 1, wc = w & 1;
    const int m0 = blockIdx.x * 128, n0 = blockIdx.y * 128;
    f32x4 acc[4][4];
#pragma unroll
    for (int i = 0; i < 4; i++)
#pragma unroll
        for (int j = 0; j < 4; j++) acc[i][j] = (f32x4){0.f, 0.f, 0.f, 0.f};

    const int rowt = t >> 3, colt = (t & 7) * 8;
    for (int k0 = 0; k0 < Kd; k0 += 64) {
#pragma unroll
        for (int i = 0; i < 4; i++) {
            int row = i * 32 + rowt;
            __builtin_amdgcn_global_load_lds(
                (const __attribute__((address_space(1))) unsigned int*)(A + (size_t)(m0 + row) * Kd + k0 + colt),
                (__attribute__((address_space(3))) unsigned int*)(As + (i * 256 + t) * 8), 16, 0, 0);
            __builtin_amdgcn_global_load_lds(
                (const __attribute__((address_space(1))) unsigned int*)(Bm + (size_t)(n0 + row) * Kd + k0 + colt),
                (__attribute__((address_space(3))) unsigned int*)(Bs + (i * 256 + t) * 8), 16, 0, 0);
        }
        asm volatile("s_waitcnt vmcnt(0)" ::: "memory");
        __syncthreads();
#pragma unroll
        for (int kk = 0; kk < 2; kk++) {
            bf16x8 af[4], bfr[4];
#pragma unroll
            for (int mi = 0; mi < 4; mi++)
                af[mi] = *reinterpret_cast<const bf16x8*>(
                    As + (wr * 64 + mi * 16 + (lane & 15)) * 64 + kk * 32 + (lane >> 4) * 8);
#pragma unroll
            for (int ni = 0; ni < 4; ni++)
                bfr[ni] = *reinterpret_cast<const bf16x8*>(
                    Bs + (wc * 64 + ni * 16 + (lane & 15)) * 64 + kk * 32 + (lane >> 4) * 8);
#pragma unroll
            for (int mi = 0; mi < 4; mi++)
#pragma unroll
                for (int ni = 0; ni < 4; ni++)
                    acc[mi][ni] = __builtin_amdgcn_mfma_f32_16x16x32_bf16(af[mi], bfr[ni], acc[mi][ni], 0, 0, 0);
        }
        __syncthreads();
    }
    const int rr = (lane >> 4) * 4, cc = lane & 15;
#pragma unroll
    for (int mi = 0; mi < 4; mi++) {
#pragma unroll
        for (int ni = 0; ni < 4; ni++) {
            int col = n0 + wc * 64 + ni * 16 + cc;
            float bv = bias ? bias[col] : 0.f;
            int rowb = m0 + wr * 64 + mi * 16 + rr;
#pragma unroll
            for (int r = 0; r < 4; r++) {
                float v = acc[mi][ni][r] + bv;
                if (BF16OUT) ((unsigned short*)Cout)[(size_t)(rowb + r) * N + col] = f2bf(v);
                else         ((float*)Cout)[(size_t)(rowb + r) * N + col] = v;
            }
        }
    }
}

// ---- group barrier: 16 blocks of one bi, one counter per (bi, step) ----
__device__ __forceinline__ void group_barrier(unsigned* bar, unsigned tgt) {
    asm volatile("s_waitcnt vmcnt(0)" ::: "memory");
    __syncthreads();
    if (threadIdx.x == 0) {
        __hip_atomic_fetch_add(bar, 1u, __ATOMIC_RELAXED, __HIP_MEMORY_SCOPE_AGENT);
        while (__hip_atomic_load(bar, __ATOMIC_RELAXED, __HIP_MEMORY_SCOPE_AGENT) < tgt)
            __builtin_amdgcn_s_sleep(1);
    }
    __syncthreads();
}

// ---------------- persistent decode: block = (bi, head, S-half) ----------------
// grid 256 x 1024 (16 waves), 1 block/CU, all co-resident. K half AND V half live
// in LDS (one-time stage, swizzled). Per step: q-proj (reg-hoisted weights), scores,
// ssum 1-float sibling exchange (spin-on-nonzero, overlapped with PV), PV, then
// gi += WfT·(pv_half*ssinv) and gh += WhhT·h  -> atomicAdd gacc (halves sum exactly:
// Wf·(pv/ss) is linear in pv). ONE 16-block barrier, replicated gates update local h.
__global__ __launch_bounds__(1024, 1) void k_decode(
    const unsigned short* __restrict__ K16, const unsigned short* __restrict__ V16,
    const unsigned short* __restrict__ Wq16, const float* __restrict__ bq,
    const unsigned short* __restrict__ WfT16, const unsigned short* __restrict__ WhhT16,
    float* __restrict__ gacc, float* __restrict__ ssx, const float* __restrict__ e_last,
    const float* __restrict__ Wout, const float* __restrict__ bout,
    float* __restrict__ dout, float* __restrict__ hfin, float* __restrict__ cross,
    unsigned* __restrict__ bars) {
    const int t = threadIdx.x, lane = t & 63, w = t >> 6;   // 16 waves
    const int bi = blockIdx.x >> 4, hd = (blockIdx.x >> 1) & 7, sh = blockIdx.x & 1;

    __shared__ char Ks[65536];     // 512 rows x 128B, slot^(row&7) swizzle
    __shared__ char Vs[65536];
    __shared__ float hsh[512];     // replicated h
    __shared__ float qsh[64];
    __shared__ float esh[512];
    __shared__ float red[1024];
    __shared__ float pvred[1024];  // [16 waves][64 d]
    __shared__ float ash[64];
    __shared__ float wred[32];
    __shared__ float sh_ssinv;

    const size_t base = (size_t)bi * (S_ * D_) + (size_t)hd * (S_ * DH_) + (size_t)sh * (512 * 64);

    // ---- one-time: stage K and V halves into LDS (swizzled); 2 threads/row ----
    {
        const int row = t >> 1, half = t & 1;
        const unsigned short* kr = K16 + base + (size_t)row * 64 + half * 32;
        const unsigned short* vr = V16 + base + (size_t)row * 64 + half * 32;
        char* krow = Ks + row * 128;
        char* vrow = Vs + row * 128;
#pragma unroll
        for (int c = 0; c < 4; c++) {
            int slot = half * 4 + c;
            *reinterpret_cast<bf16x8*>(krow + ((slot ^ (row & 7)) * 16)) =
                *reinterpret_cast<const bf16x8*>(kr + c * 8);
            *reinterpret_cast<bf16x8*>(vrow + ((slot ^ (row & 7)) * 16)) =
                *reinterpret_cast<const bf16x8*>(vr + c * 8);
        }
    }
    if (t < 512) hsh[t] = e_last[bi * 512 + t];

    // hoist q-proj weight slice into registers: (col=t&63, kp=t>>6) -> 32 bf16
    bf16x8 wq[4];
    {
        const unsigned short* wrow = Wq16 + (size_t)(hd * 64 + (t & 63)) * 512 + (t >> 6) * 32;
#pragma unroll
        for (int i = 0; i < 4; i++) wq[i] = *reinterpret_cast<const bf16x8*>(wrow + i * 8);
    }
    __syncthreads();

    for (int l = 0; l < L_; l++) {
        // ---- q-proj: 64 cols x 16 k-parts of 32 (weights in registers) ----
        {
            const float* xk = hsh + (t >> 6) * 32;
            float qa = 0.f;
#pragma unroll
            for (int kk = 0; kk < 4; kk++)
#pragma unroll
                for (int e = 0; e < 8; e++)
                    qa += xk[kk * 8 + e] * bf2f((unsigned short)wq[kk][e]);
            red[t] = qa;
        }
        __syncthreads();
        if (t < 64) {
            float s = bq[hd * 64 + t];
#pragma unroll
            for (int p = 0; p < 16; p++) s += red[p * 64 + t];
            qsh[t] = s * (1.f / 32.f);
        }
        __syncthreads();

        // ---- scores from LDS K: r = t&511, kp = t>>9 (2 threads/row) ----
        {
            const int r = t & 511, kp = t >> 9;
            const char* krow = Ks + r * 128;
            float sc = 0.f;
#pragma unroll
            for (int c = 0; c < 4; c++) {
                int slot = kp * 4 + c;
                bf16x8 kv = *reinterpret_cast<const bf16x8*>(krow + ((slot ^ (r & 7)) * 16));
#pragma unroll
                for (int e = 0; e < 8; e++)
                    sc += qsh[slot * 8 + e] * bf2f((unsigned short)kv[e]);
            }
            red[t] = sc;
        }
        __syncthreads();
        // max-free exp (scores O(0.3) by construction); per-wave sums (waves 0..7)
        if (t < 512) {
            float e = __expf(red[t] + red[t + 512]);
            esh[t] = e;
            float wsum = e;
#pragma unroll
            for (int off = 1; off < 64; off <<= 1) wsum += __shfl_xor(wsum, off);
            if (lane == 0) wred[w] = wsum;
        }
        __syncthreads();
        if (t == 0) {
            float s = 0.f;
#pragma unroll
            for (int i = 0; i < 8; i++) s += wred[i];
            wred[16] = s;   // stash own half-sum
            st_dev(ssx + (size_t)l * 256 + bi * 16 + hd * 2 + sh, s);
            asm volatile("s_waitcnt vmcnt(0)" ::: "memory");   // push to LLC now
        }

        // ---- PV from LDS V (overlaps sibling's ssum store): wave w rows [w*32,w*32+32) ----
        {
            const int o = lane & 7, sr8 = lane >> 3;
            float acc[8];
#pragma unroll
            for (int e2 = 0; e2 < 8; e2++) acc[e2] = 0.f;
#pragma unroll
            for (int i = 0; i < 4; i++) {
                int r = w * 32 + sr8 + 8 * i;
                bf16x8 vv = *reinterpret_cast<const bf16x8*>(Vs + r * 128 + ((o ^ (r & 7)) * 16));
                float ev = esh[r];
#pragma unroll
                for (int e2 = 0; e2 < 8; e2++)
                    acc[e2] += ev * bf2f((unsigned short)vv[e2]);
            }
#pragma unroll
            for (int off = 8; off < 64; off <<= 1)
#pragma unroll
                for (int e2 = 0; e2 < 8; e2++)
                    acc[e2] += __shfl_xor(acc[e2], off);
            if (lane < 8) {
#pragma unroll
                for (int e2 = 0; e2 < 8; e2++)
                    pvred[w * 64 + lane * 8 + e2] = acc[e2];
            }
        }
        __syncthreads();

        // ---- sibling ssum exchange: spin-on-nonzero (exp sums strictly > 0) ----
        if (t == 0) {
            const float* sib = ssx + (size_t)l * 256 + bi * 16 + hd * 2 + (sh ^ 1);
            float other;
            while ((other = ld_dev(sib)) == 0.f) __builtin_amdgcn_s_sleep(1);
            sh_ssinv = 1.f / (wred[16] + other);
        }
        __syncthreads();
        const float ssinv = sh_ssinv;
        if (t < 512)
            cross[((size_t)(bi * 8 + hd) * 32 + l) * 1024 + sh * 512 + t] = esh[t] * ssinv;
        if (t < 64) {
            float s = 0.f;
#pragma unroll
            for (int w2 = 0; w2 < 16; w2++) s += pvred[w2 * 64 + t];
            ash[t] = s * ssinv;   // own half's scaled pv -- halves sum via atomics
        }
        __syncthreads();

        // ---- gi over FULL 1536 outs (768 u32 pairs) from own ash; gh split by sh ----
        float* g = gacc + ((size_t)l * 16 + bi) * 3072;
        if (t < 768) {
            const unsigned int* wf = (const unsigned int*)WfT16;
            float gi0 = 0.f, gi1 = 0.f;
#pragma unroll 8
            for (int k = 0; k < 64; k++) {
                unsigned int uf = wf[(size_t)(hd * 64 + k) * 768 + t];
                float a = ash[k];
                gi0 += a * bf2f((unsigned short)(uf & 0xffffu));
                gi1 += a * bf2f((unsigned short)(uf >> 16));
            }
            atomicAdd(g + 2 * t, gi0);
            atomicAdd(g + 2 * t + 1, gi1);
        }
        if (t < 384) {
            const unsigned int* wh = (const unsigned int*)WhhT16;
            const int pair = sh * 384 + t;
            float gh0 = 0.f, gh1 = 0.f;
#pragma unroll 8
            for (int k = 0; k < 64; k++) {
                unsigned int uh = wh[(size_t)(hd * 64 + k) * 768 + pair];
                float b = hsh[hd * 64 + k];
                gh0 += b * bf2f((unsigned short)(uh & 0xffffu));
                gh1 += b * bf2f((unsigned short)(uh >> 16));
            }
            atomicAdd(g + 1536 + 2 * pair, gh0);
            atomicAdd(g + 1536 + 2 * pair + 1, gh1);
        }

        // ---- ONE barrier per step: 16 blocks of this bi ----
        group_barrier(bars + bi * 32 + l, 16u);

        // ---- replicated gates from gacc; update LDS-local h ----
        float hnew_reg = 0.f;
        if (t < 512) {
            float gi_r = ld_dev(g + t),        gi_z = ld_dev(g + 512 + t),  gi_n = ld_dev(g + 1024 + t);
            float gh_r = ld_dev(g + 1536 + t), gh_z = ld_dev(g + 2048 + t), gh_n = ld_dev(g + 2560 + t);
            float r = 1.f / (1.f + __expf(-(gi_r + gh_r)));
            float z = 1.f / (1.f + __expf(-(gi_z + gh_z)));
            float n = tanhf(gi_n + r * gh_n);
            hnew_reg = (1.f - z) * n + z * hsh[t];
        }
        __syncthreads();
        if (t < 512) hsh[t] = hnew_reg;
        __syncthreads();
        if (hd == 0 && sh == 0) {
            if (t < 512) {
                float hv = hsh[t];
                float p0 = hv * Wout[t], p1 = hv * Wout[512 + t], p2 = hv * Wout[1024 + t];
#pragma unroll
                for (int off = 1; off < 64; off <<= 1) {
                    p0 += __shfl_xor(p0, off);
                    p1 += __shfl_xor(p1, off);
                    p2 += __shfl_xor(p2, off);
                }
                if (lane == 0) { wred[w * 3] = p0; wred[w * 3 + 1] = p1; wred[w * 3 + 2] = p2; }
            }
            __syncthreads();
            if (t < 3) {
                float s = 0.f;
#pragma unroll
                for (int i = 0; i < 8; i++) s += wred[i * 3 + t];
                dout[((size_t)bi * 32 + l) * 3 + t] = s + bout[t];
            }
        }
    }
    if (hd == 0 && sh == 0 && t < 512) hfin[bi * 512 + t] = hsh[t];
}

// ---------------- launch ----------------
extern "C" void kernel_launch(void* const* d_in, const int* in_sizes, int n_in,
                              void* d_out, int out_size, void* d_ws, size_t ws_size,
                              hipStream_t stream) {
    (void)in_sizes; (void)n_in; (void)out_size; (void)ws_size;
    const float* e_all  = (const float*)d_in[0];
    const float* e_last = (const float*)d_in[1];
    const float* target = (const float*)d_in[2];
    const float* Wq     = (const float*)d_in[3];
    const float* bq     = (const float*)d_in[4];
    const float* Wk     = (const float*)d_in[5];
    const float* bk     = (const float*)d_in[6];
    const float* Wv     = (const float*)d_in[7];
    const float* bv     = (const float*)d_in[8];
    const float* Wo     = (const float*)d_in[9];
    const float* bo     = (const float*)d_in[10];
    const float* W_ih   = (const float*)d_in[11];
    const float* W_hh   = (const float*)d_in[12];
    const float* b_ih   = (const float*)d_in[13];
    const float* b_hh   = (const float*)d_in[14];
    const float* W_out  = (const float*)d_in[15];
    const float* b_out  = (const float*)d_in[16];
    float* out = (float*)d_out;

    char* ws = (char*)d_ws;
    size_t off = 0;
    auto alloc = [&](size_t bytes) -> void* {
        void* p = ws + off; off += (bytes + 255) & ~(size_t)255; return p;
    };
    unsigned short* eA     = (unsigned short*)alloc(16777216);
    unsigned short* K16    = (unsigned short*)alloc(16777216);
    unsigned short* V16    = (unsigned short*)alloc(16777216);
    unsigned short* Wk16   = (unsigned short*)alloc(524288);
    unsigned short* Wv16   = (unsigned short*)alloc(524288);
    unsigned short* Wq16   = (unsigned short*)alloc(524288);
    unsigned short* WhhT16 = (unsigned short*)alloc(1572864);   // [512][1536]
    unsigned short* Wih16  = (unsigned short*)alloc(1572864);
    unsigned short* WoT    = (unsigned short*)alloc(524288);
    unsigned short* WfT16  = (unsigned short*)alloc(1572864);   // [512][1536]
    float* Wf32  = (float*)alloc(3145728);
    float* bf_   = (float*)alloc(6144);
    float* Wd    = (float*)alloc(18432);
    float* gacc  = (float*)alloc(6291456);   // [32][16][3072]
    float* ssx   = (float*)alloc(32768);     // [32][16][8][2]
    unsigned* bars = (unsigned*)alloc(2048); // [16][32]

    float* d_outputs = out;          // [16,32,3]
    float* h_fin     = out + 1536;   // [1,16,512]
    float* cross     = out + 9728;   // [16,8,32,1024]

    // one-time prep
    hipMemsetAsync(bars, 0, 2048, stream);
    hipMemsetAsync(ssx, 0, 32768, stream);
    k_conv<<<2048, 256, 0, stream>>>(e_all, eA, 8388608);
    k_conv<<<256, 256, 0, stream>>>(Wk, Wk16, 262144);
    k_conv<<<256, 256, 0, stream>>>(Wv, Wv16, 262144);
    k_conv<<<256, 256, 0, stream>>>(Wq, Wq16, 262144);
    k_transpose_bf<<<dim3(16, 48), dim3(32, 8), 0, stream>>>(W_hh, WhhT16, 1536, 512);
    k_transpose_bf<<<dim3(16, 16), dim3(32, 8), 0, stream>>>(Wo, WoT, 512, 512);
    k_conv_wih<<<3072, 256, 0, stream>>>(W_ih, Wih16);
    k_bf_wd<<<6, 256, 0, stream>>>(W_ih, b_ih, bo, bf_, Wd);
    k_dterm2<<<6144, 256, 0, stream>>>(target, Wd, bf_, b_hh, gacc);
    k_gemm_bt<true><<<dim3(128, 4), 256, 0, stream>>>(eA, Wk16, K16, bk, 16384, 512, 512);
    k_gemm_bt<true><<<dim3(128, 4), 256, 0, stream>>>(eA, Wv16, V16, bv, 16384, 512, 512);
    k_gemm_bt<false><<<dim3(12, 4), 256, 0, stream>>>(Wih16, WoT, Wf32, nullptr, 1536, 512, 512);
    k_transpose_bf<<<dim3(16, 48), dim3(32, 8), 0, stream>>>(Wf32, WfT16, 1536, 512);

    // persistent decode: one launch, K+V LDS-resident, one 16-block barrier per step
    k_decode<<<256, 1024, 0, stream>>>(K16, V16, Wq16, bq, WfT16, WhhT16, gacc, ssx, e_last,
                                       W_out, b_out, d_outputs, h_fin, cross, bars);
}